// Round 1
// 414.084 us; speedup vs baseline: 1.1009x; 1.1009x over previous
//
#include <hip/hip_runtime.h>
#include <stdint.h>

#define N_  8
#define CK  128
#define CV  512
#define HW  900     // 30*30 queries
#define M_  7200    // 8*30*30 memory slots
#define QK_SCALE 0.08838834764831845f  // 1/sqrt(128)

typedef __attribute__((ext_vector_type(8))) short  short8;
typedef __attribute__((ext_vector_type(4))) float  floatx4;
typedef __attribute__((ext_vector_type(4))) unsigned int   uintx4;
typedef __attribute__((ext_vector_type(4))) unsigned short ushortx4;

__device__ __forceinline__ uint16_t f32_to_bf16(float x) {
    union { float f; uint32_t u; } v; v.f = x;
    return (uint16_t)((v.u + 0x7FFFu + ((v.u >> 16) & 1u)) >> 16);
}

// Direct HBM -> LDS DMA, 16 B per lane. LDS dest must be wave-uniform base
// (hardware adds lane*16); global src is per-lane.
__device__ __forceinline__ void gload_lds16(const uint16_t* g, short* l) {
    __builtin_amdgcn_global_load_lds(
        (const __attribute__((address_space(1))) void*)g,
        (__attribute__((address_space(3))) void*)l,
        16, 0, 0);
}

// ---------------------------------------------------------------- zero dsum
__global__ void k_zero(float* __restrict__ p) {
    int i = blockIdx.x * 256 + threadIdx.x;
    if (i < N_ * M_) p[i] = 0.f;
}

// ---------------------------------------------------------------- q_val copy (channels 0..511)
__global__ __launch_bounds__(256) void k_copy_qval(const float* __restrict__ qv,
                                                   float* __restrict__ out) {
    unsigned i = blockIdx.x * 256 + threadIdx.x;
    unsigned e = i * 4u;
    unsigned n = e / (CV * HW);
    unsigned off = e - n * (CV * HW);
    *(floatx4*)&out[(size_t)n * (2 * CV * HW) + off] = *(const floatx4*)&qv[e];
}

// ---------------------------------------------------------------- transpose [N][CK][L] fp32 -> [N][L][CK] bf16
__global__ __launch_bounds__(256) void k_trans(const float* __restrict__ in,
                                               uint16_t* __restrict__ outp, int L) {
    __shared__ float tile[32][33];
    const int tx = threadIdx.x & 31;
    const int ty = threadIdx.x >> 5;      // 0..7
    const int l0 = blockIdx.x * 32;
    const int c0 = blockIdx.y * 32;
    const int n  = blockIdx.z;
    const float* src = in + (size_t)n * CK * L;
    uint16_t* dst = outp + (size_t)n * L * CK;
#pragma unroll
    for (int p = 0; p < 4; p++) {
        int c = c0 + p * 8 + ty;
        int l = l0 + tx;
        float v = 0.f;
        if (l < L) v = src[(size_t)c * L + l];
        tile[p * 8 + ty][tx] = v;
    }
    __syncthreads();
#pragma unroll
    for (int p = 0; p < 4; p++) {
        int l = l0 + p * 8 + ty;
        int c = c0 + tx;
        if (l < L) dst[(size_t)l * CK + c] = f32_to_bf16(tile[tx][p * 8 + ty]);
    }
}

// ---------------------------------------------------------------- K1: aff = qkT mkT^T, exp, colsum
// Staging now via global_load_lds width=16 into LINEAR [128][64] LDS (m97 structure).
// OOB rows read garbage (stays inside workspace); garbage only reaches output
// rows/cols that the guarded epilogue never writes.
#define K1_TS 144   // C-tile stride (shorts): quads land on disjoint banks; rows 16B-aligned

__global__ __launch_bounds__(256) void k1_gemm_exp(
    const uint16_t* __restrict__ qkT,  // [N][HW][CK] bf16 (A: rows q, k=c)
    const uint16_t* __restrict__ mkT,  // [N][M][CK] bf16  (B: rows m, k=c)
    uint16_t* __restrict__ E,          // [N][HW][M] bf16 = exp(aff*scale)
    float* __restrict__ dsum)          // [N][M]
{
    __shared__ __align__(16) short smem[18432];  // ldsA(8192 sh) + ldsB(8192 sh); reused as 128x144 C-tile
    __shared__ float colsum[128];
    short* ldsA = smem;                // [128][64] linear
    short* ldsB = smem + 8192;

    const int m0 = blockIdx.x * 128;
    const int q0 = blockIdx.y * 128;
    const int n  = blockIdx.z;
    const int tid = threadIdx.x;

    if (tid < 128) colsum[tid] = 0.f;

    const int lane = tid & 63;
    const int wid  = tid >> 6;
    const int wq   = (wid >> 1) << 6;
    const int wm   = (wid & 1) << 6;
    const int fr   = lane & 15;
    const int quad = lane >> 4;

    // staging geometry: 16 chunks x 1024B; chunk (wid*4+j); lane covers 8 shorts.
    int sr[4], sc[4];
#pragma unroll
    for (int j = 0; j < 4; j++) {
        int s = ((wid * 4 + j) << 9) + lane * 8;
        sr[j] = s >> 6;        // row 0..127
        sc[j] = s & 63;        // col (shorts), multiple of 8 -> 16B aligned
    }

    floatx4 acc[4][4];
#pragma unroll
    for (int a = 0; a < 4; a++)
#pragma unroll
        for (int b = 0; b < 4; b++) acc[a][b] = (floatx4){0.f, 0.f, 0.f, 0.f};

    const uint16_t* Ab = qkT + (size_t)n * HW * CK;
    const uint16_t* Bb = mkT + (size_t)n * M_ * CK;

#pragma unroll
    for (int kc = 0; kc < 2; kc++) {
        __syncthreads();
#pragma unroll
        for (int j = 0; j < 4; j++)
            gload_lds16(&Ab[(size_t)(q0 + sr[j]) * CK + kc * 64 + sc[j]],
                        ldsA + (wid * 4 + j) * 512);
#pragma unroll
        for (int j = 0; j < 4; j++)
            gload_lds16(&Bb[(size_t)(m0 + sr[j]) * CK + kc * 64 + sc[j]],
                        ldsB + (wid * 4 + j) * 512);
        __syncthreads();   // drains vmcnt(0): staged data visible
#pragma unroll
        for (int ks = 0; ks < 2; ks++) {
            const int k0 = ks * 32 + quad * 8;
            short8 af[4], bfr[4];
#pragma unroll
            for (int t = 0; t < 4; t++)
                af[t] = *(const short8*)&ldsA[(wq + t * 16 + fr) * 64 + k0];
#pragma unroll
            for (int t = 0; t < 4; t++)
                bfr[t] = *(const short8*)&ldsB[(wm + t * 16 + fr) * 64 + k0];
#pragma unroll
            for (int tq = 0; tq < 4; tq++)
#pragma unroll
                for (int tm = 0; tm < 4; tm++)
                    acc[tq][tm] = __builtin_amdgcn_mfma_f32_16x16x32_bf16(
                        af[tq], bfr[tm], acc[tq][tm], 0, 0, 0);
        }
    }

    // ---- epilogue phase A: exp -> LDS C-tile (stride 144), colsum
    __syncthreads();   // all frag reads done; smem reusable as C-tile
    float cs[4] = {0.f, 0.f, 0.f, 0.f};
#pragma unroll
    for (int tq = 0; tq < 4; tq++) {
#pragma unroll
        for (int tm = 0; tm < 4; tm++) {
            const int col = wm + tm * 16 + fr;
#pragma unroll
            for (int i = 0; i < 4; i++) {
                const int row = wq + tq * 16 + quad * 4 + i;
                float e = __expf(acc[tq][tm][i] * QK_SCALE);
                if (q0 + row < HW) cs[tm] += e;   // guard: padded q-rows must not pollute colsum
                smem[row * K1_TS + col] = (short)f32_to_bf16(e);
            }
        }
    }
#pragma unroll
    for (int tm = 0; tm < 4; tm++) {
        float s = cs[tm];
        s += __shfl_xor(s, 16, 64);
        s += __shfl_xor(s, 32, 64);
        if (quad == 0) atomicAdd(&colsum[wm + tm * 16 + fr], s);
    }
    __syncthreads();   // C-tile complete + colsum complete

    // ---- epilogue phase B: coalesced uint4 E-writes (8 per thread)
    uint16_t* En = E + (size_t)n * HW * M_;
#pragma unroll
    for (int j = 0; j < 8; j++) {
        int idx = tid + j * 256;       // 0..2047 = 128 rows x 16 uint4
        int r   = idx >> 4;
        int c8  = (idx & 15) * 8;      // short offset in row
        if (q0 + r < HW && m0 + c8 + 8 <= M_) {
            uintx4 v = *(const uintx4*)&smem[r * K1_TS + c8];
            *(uintx4*)&En[(size_t)(q0 + r) * M_ + m0 + c8] = v;
        }
    }
    if (tid < 128) {
        const int gm = m0 + tid;
        if (gm < M_) atomicAdd(&dsum[(size_t)n * M_ + gm], colsum[tid]);
    }
}

// ---------------------------------------------------------------- dinv = 1/d
__global__ void k_dinv(const float* __restrict__ d, float* __restrict__ di) {
    int i = blockIdx.x * 256 + threadIdx.x;
    if (i < N_ * M_) di[i] = 1.0f / d[i];
}

// ---------------------------------------------------------------- mvs = bf16(mv * dinv[m])
__global__ __launch_bounds__(256) void k_mvs(
    const float* __restrict__ mval,   // [N][CV][M]
    const float* __restrict__ dinv,   // [N][M]
    uint16_t* __restrict__ mvs)       // [N][CV][M]
{
    unsigned i = blockIdx.x * 256 + threadIdx.x;
    unsigned base = i * 4u;
    unsigned n = base / (unsigned)(CV * M_);
    unsigned m = base % (unsigned)M_;
    floatx4 v  = *(const floatx4*)&mval[base];
    floatx4 di = *(const floatx4*)&dinv[n * (unsigned)M_ + m];
    ushortx4 o;
    o[0] = f32_to_bf16(v[0] * di[0]);
    o[1] = f32_to_bf16(v[1] * di[1]);
    o[2] = f32_to_bf16(v[2] * di[2]);
    o[3] = f32_to_bf16(v[3] * di[3]);
    *(ushortx4*)&mvs[base] = o;
}

// ---------------------------------------------------------------- K2 split x3
// Staging via global_load_lds width=16 into LINEAR [128][96] LDS (no pad; the
// 192B row stride puts 8 distinct-address lanes per bank on ds_read_b128 — the
// b128 throughput minimum, i.e. conflict-benign). OOB B rows (q>=900) read
// garbage inside the workspace; garbage affects only output columns the guarded
// epilogue never writes.
#define K2_SPLITS 3
#define K2_STEPS 25   // 2400 / 96

__global__ __launch_bounds__(256) void k2_split3(
    const uint16_t* __restrict__ mvs,  // [N][CV][M] bf16
    const uint16_t* __restrict__ E,    // [N][HW][M] bf16
    float* __restrict__ partials)      // [3][N][CV][HW]
{
    __shared__ __align__(16) short ldsA[128 * 96];
    __shared__ __align__(16) short ldsB[128 * 96];

    const int q0 = blockIdx.x * 128;
    const int c0 = blockIdx.y * 128;
    const int nz = blockIdx.z;
    const int n     = nz / K2_SPLITS;
    const int split = nz - n * K2_SPLITS;
    const int tid = threadIdx.x;

    const int lane = tid & 63;
    const int wid  = tid >> 6;
    const int wc   = (wid >> 1) << 6;
    const int wq   = (wid & 1) << 6;
    const int fr   = lane & 15;
    const int quad = lane >> 4;

    // staging geometry: 24 chunks x 1024B; chunk (wid*6+j); lane covers 8 shorts.
    int sr[6], sc[6];
#pragma unroll
    for (int j = 0; j < 6; j++) {
        int s = ((wid * 6 + j) << 9) + lane * 8;
        sr[j] = s / 96;            // row 0..127
        sc[j] = s - sr[j] * 96;    // col (shorts), multiple of 8 -> 16B aligned
    }

    floatx4 acc[4][4];
#pragma unroll
    for (int a = 0; a < 4; a++)
#pragma unroll
        for (int b = 0; b < 4; b++) acc[a][b] = (floatx4){0.f, 0.f, 0.f, 0.f};

    const uint16_t* Asrc = mvs + (size_t)(n * CV + c0) * M_ + split * 2400;
    const uint16_t* Bsrc = E + (size_t)n * HW * M_ + split * 2400;

    for (int step = 0; step < K2_STEPS; step++) {
        const int m0 = step * 96;
        __syncthreads();
#pragma unroll
        for (int j = 0; j < 6; j++)
            gload_lds16(&Asrc[(size_t)sr[j] * M_ + m0 + sc[j]],
                        ldsA + (wid * 6 + j) * 512);
#pragma unroll
        for (int j = 0; j < 6; j++)
            gload_lds16(&Bsrc[(size_t)(q0 + sr[j]) * M_ + m0 + sc[j]],
                        ldsB + (wid * 6 + j) * 512);
        __syncthreads();   // drains vmcnt(0): staged data visible
#pragma unroll
        for (int ks = 0; ks < 3; ks++) {
            const int k0 = ks * 32 + quad * 8;
            short8 af[4], bfr[4];
#pragma unroll
            for (int t = 0; t < 4; t++)
                af[t] = *(const short8*)&ldsA[(wc + t * 16 + fr) * 96 + k0];
#pragma unroll
            for (int t = 0; t < 4; t++)
                bfr[t] = *(const short8*)&ldsB[(wq + t * 16 + fr) * 96 + k0];
#pragma unroll
            for (int tc = 0; tc < 4; tc++)
#pragma unroll
                for (int tq = 0; tq < 4; tq++)
                    acc[tc][tq] = __builtin_amdgcn_mfma_f32_16x16x32_bf16(
                        af[tc], bfr[tq], acc[tc][tq], 0, 0, 0);
        }
    }

    float* P = partials + ((size_t)split * N_ + n) * CV * HW;
#pragma unroll
    for (int tc = 0; tc < 4; tc++) {
#pragma unroll
        for (int tq = 0; tq < 4; tq++) {
            const int gq = q0 + wq + tq * 16 + fr;
            if (gq < HW) {
#pragma unroll
                for (int i = 0; i < 4; i++) {
                    const int gc = c0 + wc + tc * 16 + quad * 4 + i;
                    P[(size_t)gc * HW + gq] = acc[tc][tq][i];
                }
            }
        }
    }
}

// ---------------------------------------------------------------- reduce 3 partials -> out mapped half
__global__ __launch_bounds__(256) void k_reduce3(const float* __restrict__ partials,
                                                 float* __restrict__ out) {
    unsigned i = blockIdx.x * 256 + threadIdx.x;
    unsigned e = i * 4u;
    unsigned n = e / (CV * HW);
    unsigned off = e - n * (CV * HW);
    const size_t stride = (size_t)N_ * CV * HW;
    const float* p = partials + (size_t)n * CV * HW + off;
    floatx4 a = *(const floatx4*)&p[0];
    floatx4 b = *(const floatx4*)&p[stride];
    floatx4 c = *(const floatx4*)&p[2 * stride];
    floatx4 s = a + b + c;
    *(floatx4*)&out[(size_t)n * (2 * CV * HW) + CV * HW + off] = s;
}

// ----------------------------------------------------------------
extern "C" void kernel_launch(void* const* d_in, const int* in_sizes, int n_in,
                              void* d_out, int out_size, void* d_ws, size_t ws_size,
                              hipStream_t stream) {
    const float* qkey = (const float*)d_in[0];  // [8][128][900]
    const float* qval = (const float*)d_in[1];  // [8][512][900]
    const float* mkey = (const float*)d_in[2];  // [8][128][7200]
    const float* mval = (const float*)d_in[3];  // [8][512][7200]
    float* out = (float*)d_out;                 // [8][1024][900]

    char* ws = (char*)d_ws;
    // E 103,680,000 | dsum 230,400 | dinv 230,400 | mvs 58,982,400 | partials 44,236,800 = 207,360,000
    // qkT/mkT alias partials (dead before k2_split3 writes partials).
    uint16_t* E        = (uint16_t*)ws;
    float*    dsum     = (float*)(ws + 103680000);
    float*    dinv     = (float*)(ws + 103910400);
    uint16_t* mvs      = (uint16_t*)(ws + 104140800);
    float*    partials = (float*)(ws + 163123200);
    uint16_t* qkT      = (uint16_t*)(ws + 163123200);
    uint16_t* mkT      = (uint16_t*)(ws + 163123200 + 1843200);

    (void)in_sizes; (void)n_in; (void)out_size; (void)ws_size;

    k_zero<<<dim3((N_ * M_ + 255) / 256), 256, 0, stream>>>(dsum);
    k_copy_qval<<<dim3((N_ * CV * HW) / 4 / 256), 256, 0, stream>>>(qval, out);
    k_trans<<<dim3(29, 4, N_), 256, 0, stream>>>(qkey, qkT, HW);
    k_trans<<<dim3(225, 4, N_), 256, 0, stream>>>(mkey, mkT, M_);
    k1_gemm_exp<<<dim3(57, 8, N_), 256, 0, stream>>>(qkT, mkT, E, dsum);
    k_dinv<<<dim3((N_ * M_ + 255) / 256), 256, 0, stream>>>(dsum, dinv);
    k_mvs<<<dim3((N_ * CV * M_) / 4 / 256), 256, 0, stream>>>(mval, dinv, mvs);
    k2_split3<<<dim3(8, 4, N_ * K2_SPLITS), 256, 0, stream>>>(mvs, E, partials);
    k_reduce3<<<dim3((N_ * CV * HW) / 4 / 256), 256, 0, stream>>>(partials, out);
}